// Round 6
// baseline (157.553 us; speedup 1.0000x reference)
//
#include <hip/hip_runtime.h>
#include <math.h>

#define EPSV 1e-5f

static constexpr int Ls = 2048, Hh = 8;
static constexpr int NCH = 64, T = 32;   // 64 chunks of 32 along L

typedef unsigned short u16;
using frag  = __attribute__((ext_vector_type(8))) short;   // 8 x bf16 (4 VGPRs)
using f32x4 = __attribute__((ext_vector_type(4))) float;

__device__ __forceinline__ void split_bf16(float v, u16& hi, u16& lo) {
    const unsigned u = __float_as_uint(v);
    hi = (u16)(u >> 16);
    const float hf = __uint_as_float((unsigned)hi << 16);
    lo = (u16)(__float_as_uint(v - hf) >> 16);
}

__device__ __forceinline__ unsigned pk2(u16 a, u16 b) {
    return (unsigned)a | ((unsigned)b << 16);
}

__device__ __forceinline__ void split8(const float4& a, const float4& b,
                                       uint4& hi, uint4& lo) {
    u16 h[8], l[8];
    const float f[8] = {a.x, a.y, a.z, a.w, b.x, b.y, b.z, b.w};
#pragma unroll
    for (int i = 0; i < 8; ++i) split_bf16(f[i], h[i], l[i]);
    hi = make_uint4(pk2(h[0], h[1]), pk2(h[2], h[3]), pk2(h[4], h[5]), pk2(h[6], h[7]));
    lo = make_uint4(pk2(l[0], l[1]), pk2(l[2], l[3]), pk2(l[4], l[5]), pk2(l[6], l[7]));
}

// =====================================================================
// qkv_fused: split-bf16 MFMA GEMM for q,k,v + fused chunk_sum epilogue
// grid: (64 row-tiles, 4 head-pairs) x 256 threads (4 waves)
// =====================================================================
__global__ __launch_bounds__(256) void qkv_fused(
    const float* __restrict__ x,
    const float* __restrict__ wq, const float* __restrict__ wk, const float* __restrict__ wv,
    const float* __restrict__ bq, const float* __restrict__ bk, const float* __restrict__ bv,
    const float* __restrict__ wg_w, const float* __restrict__ wg_b,
    const float* __restrict__ kvs, const float* __restrict__ qks,
    float* __restrict__ qh, float* __restrict__ kh, float* __restrict__ vh,
    float* __restrict__ simG, float* __restrict__ gG,
    float* __restrict__ ZcT, float* __restrict__ mT, float* __restrict__ sT,
    float* __restrict__ gTt)
{
    constexpr int LDK = 40;     // u16 per staged row (80 B, 16B-aligned)
    constexpr int LDT = 68;     // f32 per tile row (272 B = 17*16: float4-aligned rows)
    // staging (40960 B) aliases tiles (52224 B); phases separated by barriers
    __shared__ __align__(16) float smemf[3 * 64 * LDT];
    __shared__ __align__(16) float wkT[2][32 * 36];   // [h][e*36+d], rows 144 B
    __shared__ float lsim[2][64], lg2[2][64];

    u16* As_hi = (u16*)smemf;          // 2560 u16
    u16* As_lo = As_hi + 2560;
    u16* Wst   = As_lo + 2560;         // per weight w: hi at w*5120, lo at +2560
    float* Qt = smemf;
    float* Kt = Qt + 64 * LDT;
    float* Vt = Kt + 64 * LDT;

    const int tid = threadIdx.x;
    const int mt = blockIdx.x, nt = blockIdx.y;
    const int m0 = mt * 64, ncol0 = nt * 64;
    const int bidx = m0 >> 11, lg = m0 & (Ls - 1);
    const int wave = tid >> 6, lane = tid & 63;
    const int l15 = lane & 15, quad = lane >> 4;
    const int srow = tid >> 2, sk = (tid & 3) * 8;

    // wg_w * kvs, transposed to [e][d] for float4 dot in Phase G
    for (int i = tid; i < 2048; i += 256) {
        const int h = i >> 10, de = i & 1023;
        const int d = de >> 5, e = de & 31;
        wkT[h][e * 36 + d] = wg_w[de] * kvs[(nt * 2 + h) * 1024 + de];
    }

    const float* Wsrc[3] = {wq, wk, wv};
    f32x4 acc[3][4] = {};

    for (int k0 = 0; k0 < 256; k0 += 32) {
        const float4 a0 = *(const float4*)&x[(size_t)(m0 + srow) * 256 + k0 + sk];
        const float4 a1 = *(const float4*)&x[(size_t)(m0 + srow) * 256 + k0 + sk + 4];
        float4 w0[3], w1[3];
#pragma unroll
        for (int w = 0; w < 3; ++w) {
            w0[w] = *(const float4*)&Wsrc[w][(size_t)(ncol0 + srow) * 256 + k0 + sk];
            w1[w] = *(const float4*)&Wsrc[w][(size_t)(ncol0 + srow) * 256 + k0 + sk + 4];
        }
        __syncthreads();
        {
            uint4 hi, lo;
            split8(a0, a1, hi, lo);
            *(uint4*)&As_hi[srow * LDK + sk] = hi;
            *(uint4*)&As_lo[srow * LDK + sk] = lo;
#pragma unroll
            for (int w = 0; w < 3; ++w) {
                split8(w0[w], w1[w], hi, lo);
                *(uint4*)&Wst[w * 5120 + srow * LDK + sk] = hi;
                *(uint4*)&Wst[w * 5120 + 2560 + srow * LDK + sk] = lo;
            }
        }
        __syncthreads();

        const frag ah = *(const frag*)&As_hi[(wave * 16 + l15) * LDK + quad * 8];
        const frag al = *(const frag*)&As_lo[(wave * 16 + l15) * LDK + quad * 8];
#pragma unroll
        for (int w = 0; w < 3; ++w)
#pragma unroll
            for (int cf = 0; cf < 4; ++cf) {
                const u16* bp = &Wst[w * 5120 + (cf * 16 + l15) * LDK + quad * 8];
                const frag bh = *(const frag*)bp;
                const frag bl = *(const frag*)(bp + 2560);
                acc[w][cf] = __builtin_amdgcn_mfma_f32_16x16x32_bf16(ah, bh, acc[w][cf], 0, 0, 0);
                acc[w][cf] = __builtin_amdgcn_mfma_f32_16x16x32_bf16(ah, bl, acc[w][cf], 0, 0, 0);
                acc[w][cf] = __builtin_amdgcn_mfma_f32_16x16x32_bf16(al, bh, acc[w][cf], 0, 0, 0);
            }
    }
    __syncthreads();   // staging dead; write tiles (aliased region)

    {
        float* tiles[3] = {Qt, Kt, Vt};
        const float* biases[3] = {bq, bk, bv};
#pragma unroll
        for (int w = 0; w < 3; ++w)
#pragma unroll
            for (int cf = 0; cf < 4; ++cf) {
                const int col = cf * 16 + l15;
                const float bias = biases[w][ncol0 + col];
#pragma unroll
                for (int r = 0; r < 4; ++r) {
                    const int m = wave * 16 + quad * 4 + r;
                    tiles[w][m * LDT + col] = acc[w][cf][r] + bias;
                }
            }
    }
    __syncthreads();

    // ---- Phase N: normalize k,v in place; sim (float4 LDS) ----
    if (tid < 128) {
        const int h = tid >> 6, l = tid & 63;
        const int rb = l * LDT + h * 32;
        float4 kr[8], vr[8];
        float ksum = 0.f, vsum = 0.f, qk = 0.f;
#pragma unroll
        for (int e4 = 0; e4 < 8; ++e4) {
            kr[e4] = *(const float4*)&Kt[rb + e4 * 4];
            vr[e4] = *(const float4*)&Vt[rb + e4 * 4];
            const float4 q4 = *(const float4*)&Qt[rb + e4 * 4];
            ksum += kr[e4].x * kr[e4].x + kr[e4].y * kr[e4].y + kr[e4].z * kr[e4].z + kr[e4].w * kr[e4].w;
            vsum += vr[e4].x * vr[e4].x + vr[e4].y * vr[e4].y + vr[e4].z * vr[e4].z + vr[e4].w * vr[e4].w;
            qk   += q4.x * kr[e4].x + q4.y * kr[e4].y + q4.z * kr[e4].z + q4.w * kr[e4].w;
        }
        const float kscale = 1.f / fmaxf(sqrtf(ksum), 1e-12f);
        const float vscale = 1.f / fmaxf(sqrtf(vsum), 1e-12f);
#pragma unroll
        for (int e4 = 0; e4 < 8; ++e4) {
            float4 k4 = kr[e4], v4 = vr[e4];
            k4.x *= kscale; k4.y *= kscale; k4.z *= kscale; k4.w *= kscale;
            v4.x *= vscale; v4.y *= vscale; v4.z *= vscale; v4.w *= vscale;
            *(float4*)&Kt[rb + e4 * 4] = k4;
            *(float4*)&Vt[rb + e4 * 4] = v4;
        }
        const float sim = qk * qks[nt * 2 + h];
        lsim[h][l] = sim;
        simG[(size_t)(bidx * 8 + nt * 2 + h) * Ls + lg + l] = sim;
    }
    __syncthreads();

    // ---- Phase copy: q, kn, vn to global (float4) ----
    {
        const float* tl[3] = {Qt, Kt, Vt};
        float* gl[3] = {qh, kh, vh};
#pragma unroll
        for (int arr = 0; arr < 3; ++arr)
#pragma unroll
            for (int it = 0; it < 4; ++it) {
                const int idx = it * 1024 + tid * 4;
                const int h = idx >> 11, rem = idx & 2047;
                const int l = rem >> 5, e4 = rem & 31;
                const float4 v = *(const float4*)&tl[arr][l * LDT + h * 32 + e4];
                *(float4*)&gl[arr][(size_t)(bidx * 8 + nt * 2 + h) * 65536 +
                                   (size_t)(lg + l) * 32 + e4] = v;
            }
    }

    // ---- Phase G: gate per (h,l); 2 threads per task; float4 LDS dots ----
    {
        const int task = tid >> 1, half = tid & 1;
        const int h = task >> 6, l = task & 63;
        float4 vr[8];
#pragma unroll
        for (int d4 = 0; d4 < 8; ++d4)
            vr[d4] = *(const float4*)&Vt[l * LDT + h * 32 + d4 * 4];
        float u = 0.f;
        const int e0 = half * 16;
#pragma unroll 4
        for (int e = e0; e < e0 + 16; ++e) {
            float4 s4 = make_float4(0.f, 0.f, 0.f, 0.f);
#pragma unroll
            for (int d4 = 0; d4 < 8; ++d4) {
                const float4 w4 = *(const float4*)&wkT[h][e * 36 + d4 * 4];
                s4.x = fmaf(vr[d4].x, w4.x, s4.x);
                s4.y = fmaf(vr[d4].y, w4.y, s4.y);
                s4.z = fmaf(vr[d4].z, w4.z, s4.z);
                s4.w = fmaf(vr[d4].w, w4.w, s4.w);
            }
            u = fmaf(s4.x + s4.y + s4.z + s4.w, Kt[l * LDT + h * 32 + e], u);
        }
        u += __shfl_xor(u, 1);
        if (half == 0) {
            const float r = fmaxf(u + wg_b[0], 0.f);
            const float g = r * r + EPSV;
            lg2[h][l] = g;
            gG[(size_t)(bidx * 8 + nt * 2 + h) * Ls + lg + l] = g;
        }
    }
    __syncthreads();

    // ---- Phase Z: chunk-Z totals (float4 Kt reads) ----
    {
        const int d = tid >> 3, e4m = (tid & 7) * 4;
#pragma unroll
        for (int h = 0; h < 2; ++h)
#pragma unroll
            for (int cc = 0; cc < 2; ++cc) {
                float4 z4 = make_float4(0.f, 0.f, 0.f, 0.f);
#pragma unroll 8
                for (int l = 0; l < 32; ++l) {
                    const int lr = cc * 32 + l;
                    const float gv = lg2[h][lr] * Vt[lr * LDT + h * 32 + d];
                    const float4 k4 = *(const float4*)&Kt[lr * LDT + h * 32 + e4m];
                    z4.x = fmaf(gv, k4.x, z4.x);
                    z4.y = fmaf(gv, k4.y, z4.y);
                    z4.z = fmaf(gv, k4.z, z4.z);
                    z4.w = fmaf(gv, k4.w, z4.w);
                }
                const int bhg = bidx * 8 + nt * 2 + h;
                const int cg = (lg >> 5) + cc;
                *(float4*)&ZcT[((size_t)bhg * NCH + cg) * 1024 + d * 32 + e4m] = z4;
            }
    }

    // ---- (m,s,g) chunk totals: wave w handles (h = w>>1, cc = w&1) ----
    {
        const int h = wave >> 1, cc = wave & 1;
        if (lane < 32) {
            const int lr = cc * 32 + lane;
            float m = lsim[h][lr], s = 1.f, g = lg2[h][lr];
#pragma unroll
            for (int off = 16; off; off >>= 1) {
                const float mo = __shfl_xor(m, off);
                const float so = __shfl_xor(s, off);
                const float mn = fmaxf(m, mo);
                s = s * __expf(m - mn) + so * __expf(mo - mn);
                m = mn;
                g += __shfl_xor(g, off);
            }
            if (lane == 0) {
                const int bhg = bidx * 8 + nt * 2 + h;
                const int cg = (lg >> 5) + cc;
                mT[bhg * NCH + cg] = m;
                sT[bhg * NCH + cg] = s;
                gTt[bhg * NCH + cg] = g;
            }
        }
    }
}

// ---------------- prefix: parallel Hillis-Steele scan over chunks in LDS ----------
// grid (16 bh, 16 seg) x 256. Block scans 64 elements x 64 chunks.
__global__ __launch_bounds__(256) void prefix_kernel(
    float* __restrict__ Zc, float* __restrict__ mT, float* __restrict__ sT,
    float* __restrict__ gTt,
    const float* __restrict__ kvs, float* __restrict__ aW, float* __restrict__ bW,
    int* __restrict__ flagW)
{
    __shared__ float sc[64 * 64];
    const int bh = blockIdx.x, seg = blockIdx.y;
    const int tid = threadIdx.x;
    float* Zb = Zc + (size_t)bh * NCH * 1024 + seg * 64;

#pragma unroll
    for (int it = 0; it < 16; ++it) {
        const int idx = it * 256 + tid;
        const int cc = idx >> 6, e = idx & 63;
        sc[idx] = Zb[(size_t)cc * 1024 + e];
    }
    __syncthreads();
#pragma unroll
    for (int st = 1; st < 64; st <<= 1) {
        float tmp[16];
#pragma unroll
        for (int it = 0; it < 16; ++it) {
            const int idx = it * 256 + tid;
            tmp[it] = ((idx >> 6) >= st) ? sc[idx - st * 64] : 0.f;
        }
        __syncthreads();
#pragma unroll
        for (int it = 0; it < 16; ++it) sc[it * 256 + tid] += tmp[it];
        __syncthreads();
    }
#pragma unroll
    for (int it = 0; it < 16; ++it) {
        const int idx = it * 256 + tid;
        const int cc = idx >> 6, e = idx & 63;
        Zb[(size_t)cc * 1024 + e] = cc ? sc[idx - 64] : 0.f;   // exclusive
    }

    if (seg == 0 && tid < 64) {
        float m = mT[bh * NCH + tid], s = sT[bh * NCH + tid], g = gTt[bh * NCH + tid];
#pragma unroll
        for (int off = 1; off < 64; off <<= 1) {
            const float mo = __shfl_up(m, off);
            const float so = __shfl_up(s, off);
            const float go = __shfl_up(g, off);
            if (tid >= off) {
                const float mn = fmaxf(m, mo);
                s = s * __expf(m - mn) + so * __expf(mo - mn);
                m = mn;
                g += go;
            }
        }
        float me = __shfl_up(m, 1), se = __shfl_up(s, 1), ge = __shfl_up(g, 1);
        if (tid == 0) { me = -1e30f; se = 0.f; ge = 0.f; }
        mT[bh * NCH + tid] = me;
        sT[bh * NCH + tid] = se;
        gTt[bh * NCH + tid] = ge;
    }

    if (bh == 0 && seg == 1) {
        const int h = tid >> 5, e = tid & 31;
        const float* K = kvs + h * 1024;
        const float k00 = K[0];
        int ok = (k00 != 0.0f);
        for (int d = 0; d < 32; ++d) {
            const float lhs = K[d * 32 + e] * k00;
            const float rhs = K[d * 32] * K[e];
            const float diff = fabsf(lhs - rhs);
            if (diff > 1e-6f * fmaxf(fmaxf(fabsf(lhs), fabsf(rhs)), 1e-20f)) ok = 0;
        }
        aW[h * 32 + e] = K[e * 32];
        bW[h * 32 + e] = (k00 != 0.0f) ? K[e] / k00 : 0.f;
        const int allok = __syncthreads_and(ok);
        if (tid == 0) flagW[0] = allok;
    }
}

// ---------------- chunk_out: 256 threads, thread owns (l, 4 e's); b128 LDS ----------
__global__ __launch_bounds__(256) void chunk_out_kernel(
    const float* __restrict__ qh, const float* __restrict__ knG, const float* __restrict__ vnG,
    const float* __restrict__ simG, const float* __restrict__ gG,
    const float* __restrict__ kvs,
    const float* __restrict__ ZcP, const float* __restrict__ mP,
    const float* __restrict__ sP, const float* __restrict__ gP,
    const float* __restrict__ aW, const float* __restrict__ bW,
    const int* __restrict__ flagW,
    u16* __restrict__ chi, u16* __restrict__ clo)
{
    __shared__ __align__(16) float qa[1024], knb[1024], zp[1024], sW[1024];
    __shared__ __align__(16) float vnT[32 * 36];   // [d][j], rows 144 B
    __shared__ float lkvs[1024];                    // fallback only
    __shared__ float lgS[32], lsimS[32], lwgt[32];
    const int tid = threadIdx.x;
    const int c = blockIdx.x, bh = blockIdx.y, h = bh & 7, b = bh >> 3;
    const int l = tid >> 3, e4 = (tid & 7) * 4;
    const size_t base4 = ((size_t)bh * Ls + (size_t)c * T) * 8 + tid;   // float4 idx
    const int flag = flagW[0];

    const float4 qv4 = ((const float4*)qh)[base4];
    const float4 kn4 = ((const float4*)knG)[base4];
    const float4 vn4 = ((const float4*)vnG)[base4];
    const float4 z4  = ((const float4*)ZcP)[((size_t)bh * NCH + c) * 256 + tid];
    const float4 la4 = *(const float4*)&aW[h * 32 + e4];
    const float4 lb4 = *(const float4*)&bW[h * 32 + e4];
    if (tid < 32) {
        lgS[tid] = gG[bh * Ls + c * T + tid];
        lsimS[tid] = simG[bh * Ls + c * T + tid];
    }
    if (!flag) {
        *(float4*)&lkvs[tid * 4] = *(const float4*)&kvs[h * 1024 + tid * 4];
    }
    {
        float4 q = qv4, k = kn4;
        if (flag) {
            q.x *= la4.x; q.y *= la4.y; q.z *= la4.z; q.w *= la4.w;
            k.x *= lb4.x; k.y *= lb4.y; k.z *= lb4.z; k.w *= lb4.w;
        }
        *(float4*)&qa[l * 32 + e4] = q;
        *(float4*)&knb[l * 32 + e4] = k;
        *(float4*)&zp[tid * 4] = z4;
        vnT[(e4 + 0) * 36 + l] = vn4.x;
        vnT[(e4 + 1) * 36 + l] = vn4.y;
        vnT[(e4 + 2) * 36 + l] = vn4.z;
        vnT[(e4 + 3) * 36 + l] = vn4.w;
    }
    __syncthreads();

    if (tid < 32) {
        float m = lsimS[tid], s = 1.f, g = lgS[tid];
#pragma unroll
        for (int off = 1; off < 32; off <<= 1) {
            const float mo = __shfl_up(m, off);
            const float so = __shfl_up(s, off);
            const float go = __shfl_up(g, off);
            if (tid >= off) {
                const float mn = fmaxf(m, mo);
                s = s * __expf(m - mn) + so * __expf(mo - mn);
                m = mn;
                g += go;
            }
        }
        const float mp = mP[bh * NCH + c];
        const float sp = sP[bh * NCH + c];
        const float gp = gP[bh * NCH + c];
        const float mn = fmaxf(mp, m);
        s = sp * __expf(mp - mn) + s * __expf(m - mn);
        m = mn;
        g += gp;
        const float sw = __expf(lsimS[tid] - m) / (s + EPSV);
        const float sig = 1.f / (1.f + __expf(-sw));
        lwgt[tid] = (1.f + sw * sig) / (g + EPSV);
    }

    float4 y4 = make_float4(0.f, 0.f, 0.f, 0.f);
    if (flag) {
        // qa row in registers (broadcast among the 8 lanes sharing l)
        float qrow[32];
#pragma unroll
        for (int d4 = 0; d4 < 8; ++d4)
            *(float4*)&qrow[d4 * 4] = *(const float4*)&qa[l * 32 + d4 * 4];
        float4 s4 = make_float4(0.f, 0.f, 0.f, 0.f);
#pragma unroll 8
        for (int d = 0; d < 32; ++d) {
            const float qd = qrow[d];
            const float4 v4 = *(const float4*)&vnT[d * 36 + e4];
            const float4 p4 = *(const float4*)&zp[d * 32 + e4];
            s4.x = fmaf(qd, v4.x, s4.x);
            s4.y = fmaf(qd, v4.y, s4.y);
            s4.z = fmaf(qd, v4.z, s4.z);
            s4.w = fmaf(qd, v4.w, s4.w);
            y4.x = fmaf(qd, p4.x, y4.x);
            y4.y = fmaf(qd, p4.y, y4.y);
            y4.z = fmaf(qd, p4.z, y4.z);
            y4.w = fmaf(qd, p4.w, y4.w);
        }
        y4.x *= lb4.x; y4.y *= lb4.y; y4.z *= lb4.z; y4.w *= lb4.w;
        const float4 lg4 = *(const float4*)&lgS[e4];
        float4 sm;
        sm.x = (e4 + 0 <= l) ? lg4.x * s4.x : 0.f;
        sm.y = (e4 + 1 <= l) ? lg4.y * s4.y : 0.f;
        sm.z = (e4 + 2 <= l) ? lg4.z * s4.z : 0.f;
        sm.w = (e4 + 3 <= l) ? lg4.w * s4.w : 0.f;
        *(float4*)&sW[l * 32 + e4] = sm;
        __syncthreads();
        float srow[32];
#pragma unroll
        for (int j4 = 0; j4 < 8; ++j4)
            *(float4*)&srow[j4 * 4] = *(const float4*)&sW[l * 32 + j4 * 4];
#pragma unroll 8
        for (int j = 0; j < 32; ++j) {
            const float sj = srow[j];
            const float4 k4 = *(const float4*)&knb[j * 32 + e4];
            y4.x = fmaf(sj, k4.x, y4.x);
            y4.y = fmaf(sj, k4.y, y4.y);
            y4.z = fmaf(sj, k4.z, y4.z);
            y4.w = fmaf(sj, k4.w, y4.w);
        }
    } else {
        __syncthreads();   // match barrier count
        float* yp = &y4.x;
#pragma unroll
        for (int i = 0; i < 4; ++i) {
            const int e = e4 + i;
            float qe[32];
#pragma unroll
            for (int d = 0; d < 32; ++d)
                qe[d] = qa[l * 32 + d] * lkvs[d * 32 + e];
            float y = 0.f;
#pragma unroll
            for (int d = 0; d < 32; ++d)
                y = fmaf(qe[d], zp[d * 32 + e], y);
            for (int j = 0; j < 32; ++j) {
                float s = 0.f;
#pragma unroll
                for (int d = 0; d < 32; ++d)
                    s = fmaf(qe[d], vnT[d * 36 + j], s);
                if (j <= l) y = fmaf(lgS[j] * s, knb[j * 32 + e], y);
            }
            yp[i] = y;
        }
    }
    const float w = lwgt[l];
    ushort4 hi4, lo4;
    split_bf16(y4.x * w, hi4.x, lo4.x);
    split_bf16(y4.y * w, hi4.y, lo4.y);
    split_bf16(y4.z * w, hi4.z, lo4.z);
    split_bf16(y4.w * w, hi4.w, lo4.w);
    const size_t oidx = ((size_t)(b * Ls + c * T + l)) * 256 + h * 32 + e4;
    *(ushort4*)&chi[oidx] = hi4;
    *(ushort4*)&clo[oidx] = lo4;
}

// ---------------- out_gemm: 64x64-tile split-bf16 MFMA, W split on the fly ----------
__global__ __launch_bounds__(256) void out_gemm(
    const u16* __restrict__ Ahi, const u16* __restrict__ Alo,
    const float* __restrict__ wo, const float* __restrict__ bo,
    float* __restrict__ out)
{
    constexpr int LDK = 40;
    __shared__ __align__(16) u16 As_hi[64 * LDK];
    __shared__ __align__(16) u16 As_lo[64 * LDK];
    __shared__ __align__(16) u16 Ws_hi[64 * LDK];
    __shared__ __align__(16) u16 Ws_lo[64 * LDK];

    const int tid = threadIdx.x;
    const int mt = blockIdx.x, nt = blockIdx.y;
    const int m0 = mt * 64, ncol0 = nt * 64;
    const int wave = tid >> 6, lane = tid & 63;
    const int l15 = lane & 15, quad = lane >> 4;
    const int srow = tid >> 2, sk = (tid & 3) * 8;

    f32x4 acc[4] = {};

    for (int k0 = 0; k0 < 256; k0 += 32) {
        const uint4 ah = *(const uint4*)&Ahi[(size_t)(m0 + srow) * 256 + k0 + sk];
        const uint4 al = *(const uint4*)&Alo[(size_t)(m0 + srow) * 256 + k0 + sk];
        const float4 w0 = *(const float4*)&wo[(size_t)(ncol0 + srow) * 256 + k0 + sk];
        const float4 w1 = *(const float4*)&wo[(size_t)(ncol0 + srow) * 256 + k0 + sk + 4];
        __syncthreads();
        uint4 whi, wlo;
        split8(w0, w1, whi, wlo);
        *(uint4*)&As_hi[srow * LDK + sk] = ah;
        *(uint4*)&As_lo[srow * LDK + sk] = al;
        *(uint4*)&Ws_hi[srow * LDK + sk] = whi;
        *(uint4*)&Ws_lo[srow * LDK + sk] = wlo;
        __syncthreads();

        const frag fah = *(const frag*)&As_hi[(wave * 16 + l15) * LDK + quad * 8];
        const frag fal = *(const frag*)&As_lo[(wave * 16 + l15) * LDK + quad * 8];
#pragma unroll
        for (int cf = 0; cf < 4; ++cf) {
            const frag fbh = *(const frag*)&Ws_hi[(cf * 16 + l15) * LDK + quad * 8];
            const frag fbl = *(const frag*)&Ws_lo[(cf * 16 + l15) * LDK + quad * 8];
            acc[cf] = __builtin_amdgcn_mfma_f32_16x16x32_bf16(fah, fbh, acc[cf], 0, 0, 0);
            acc[cf] = __builtin_amdgcn_mfma_f32_16x16x32_bf16(fah, fbl, acc[cf], 0, 0, 0);
            acc[cf] = __builtin_amdgcn_mfma_f32_16x16x32_bf16(fal, fbh, acc[cf], 0, 0, 0);
        }
    }

#pragma unroll
    for (int cf = 0; cf < 4; ++cf) {
        const int o = ncol0 + cf * 16 + l15;
        const float bias = bo[o];
#pragma unroll
        for (int r = 0; r < 4; ++r) {
            const int rm = m0 + wave * 16 + quad * 4 + r;
            out[(size_t)rm * 256 + o] = acc[cf][r] + bias;
        }
    }
}

extern "C" void kernel_launch(void* const* d_in, const int* in_sizes, int n_in,
                              void* d_out, int out_size, void* d_ws, size_t ws_size,
                              hipStream_t stream) {
    const float* x    = (const float*)d_in[0];
    const float* wq_w = (const float*)d_in[1];
    const float* wq_b = (const float*)d_in[2];
    const float* wk_w = (const float*)d_in[3];
    const float* wk_b = (const float*)d_in[4];
    const float* wv_w = (const float*)d_in[5];
    const float* wv_b = (const float*)d_in[6];
    const float* wo_w = (const float*)d_in[7];
    const float* wo_b = (const float*)d_in[8];
    const float* wg_w = (const float*)d_in[9];
    const float* wg_b = (const float*)d_in[10];
    const float* kvs  = (const float*)d_in[11];
    const float* qks  = (const float*)d_in[12];
    float* out = (float*)d_out;

    u16* chi = (u16*)d_ws;                 // 1048576 u16
    u16* clo = chi + 1048576;              // 1048576 u16
    float* qh   = (float*)(clo + 1048576); // 1048576 f32
    float* kh   = qh + 1048576;
    float* vh   = kh + 1048576;
    float* ZcT  = vh + 1048576;            // 1048576
    float* simG = ZcT + 1048576;           // 32768
    float* gG   = simG + 32768;            // 32768
    float* mT   = gG + 32768;              // 1024
    float* sT   = mT + 1024;
    float* gTt  = sT + 1024;
    float* aW   = gTt + 1024;              // 256
    float* bW   = aW + 256;                // 256
    int* flagW  = (int*)(bW + 256);
    // total ~20.5 MB

    qkv_fused<<<dim3(64, 4), 256, 0, stream>>>(
        x, wq_w, wk_w, wv_w, wq_b, wk_b, wv_b, wg_w, wg_b, kvs, qks,
        qh, kh, vh, simG, gG, ZcT, mT, sT, gTt);
    prefix_kernel<<<dim3(16, 16), 256, 0, stream>>>(
        ZcT, mT, sT, gTt, kvs, aW, bW, flagW);
    chunk_out_kernel<<<dim3(NCH, 16), 256, 0, stream>>>(
        qh, kh, vh, simG, gG, kvs, ZcT, mT, sT, gTt, aW, bW, flagW, chi, clo);
    out_gemm<<<dim3(64, 4), 256, 0, stream>>>(
        chi, clo, wo_w, wo_b, out);
}